// Round 1
// baseline (187.755 us; speedup 1.0000x reference)
//
#include <hip/hip_runtime.h>
#include <hip/hip_bf16.h>

#define C_IN  64
#define C_OUT 128
#define KK    27
#define HH    100000
#define TB    1563         // transpose blocks = ceil(HH/64)
#define WB    108          // weight-convert blocks (108*2048 = 221184 elems)
#define BN    128          // h tile per block
#define NBLK  782          // ceil(HH/128)

typedef __attribute__((ext_vector_type(8))) short s8v;    // 8 bf16 (MFMA A/B frag)
typedef __attribute__((ext_vector_type(4))) float f32x4;  // MFMA C/D frag

__device__ inline unsigned short f2bf(float f) {
    __hip_bfloat16 h = __float2bfloat16(f);
    return *reinterpret_cast<unsigned short*>(&h);
}

__device__ inline void dma16(const void* g, void* l) {
    __builtin_amdgcn_global_load_lds((const __attribute__((address_space(1))) void*)g,
                                     (__attribute__((address_space(3))) void*)l, 16, 0, 0);
}

// ---- prep: transpose x -> xt (bf16, [h][64] plain), W -> wk (bf16, [k][o][64] XOR-swizzled) ----
// wk physical chunk pj (16B unit) holds logical chunk pj ^ (o&7).
__global__ __launch_bounds__(256) void prep_kernel(const float* __restrict__ x,
                                                   const float* __restrict__ w,
                                                   unsigned short* __restrict__ xt,
                                                   unsigned short* __restrict__ wk) {
    const int tid = threadIdx.x;
    if (blockIdx.x < TB) {
        __shared__ __align__(16) unsigned short ts[64 * 72];
        const int hbase = blockIdx.x * 64;
        #pragma unroll
        for (int it = 0; it < 16; ++it) {
            int i = it * 256 + tid;           // 64h x 64c
            int c = i >> 6, hl = i & 63;
            int hg = hbase + hl;
            float v = (hg < HH) ? x[(size_t)c * HH + hg] : 0.f;  // coalesced in h
            ts[hl * 72 + c] = f2bf(v);
        }
        __syncthreads();
        #pragma unroll
        for (int it = 0; it < 2; ++it) {
            int u = it * 256 + tid;           // 64 rows x 8 chunks of 16B
            int hl = u >> 3, part = u & 7;
            int hg = hbase + hl;
            if (hg < HH)
                *(int4*)&xt[(size_t)hg * 64 + part * 8] = *(const int4*)&ts[hl * 72 + part * 8];
        }
    } else {
        int b = blockIdx.x - TB;
        int base = b * 2048 + tid;
        #pragma unroll
        for (int j = 0; j < 8; ++j) {
            int t = base + j * 256;           // wk index: t = k*8192 + o*64 + jj
            int jj = t & 63, o = (t >> 6) & 127, kx = t >> 13;
            int lc = (jj >> 3) ^ (o & 7);     // logical chunk
            int c  = lc * 8 + (jj & 7);
            wk[t] = f2bf(w[(size_t)o * (C_IN * KK) + c * KK + kx]);
        }
    }
}

// ---------------- main gather-GEMM ----------------
// block 256 thr = 4 waves; tile M=128 (all o) x N=128 h; wave w: h strip [w*32, w*32+32)
// LDS = 13.8KB neigh + 32KB w_s -> 3 blocks/CU resident (vs 2 before); grid 782 blocks
// fills that capacity (~12 waves/CU) so the random-gather L3 latency is hidden by TLP.
__global__ __launch_bounds__(256, 3) void conv_main(const unsigned short* __restrict__ xt,
                                                    const unsigned short* __restrict__ wk,
                                                    const int* __restrict__ neigh,
                                                    float* __restrict__ out) {
    __shared__ int neigh_s[BN * KK];                             // 13824 B, [h][k]
    __shared__ __align__(16) unsigned short w_s[2][128 * 64];    // 2 x 16 KB, XOR-swizzled rows

    const int tid  = threadIdx.x;
    const int wave = tid >> 6;
    const int lane = tid & 63;
    const int col  = lane & 15;
    const int quad = lane >> 4;
    const int hbase = blockIdx.x * BN;

    // ---- issue W DMA for k=0 into buf 0 first (overlaps with neigh staging) ----
    #pragma unroll
    for (int i = 0; i < 4; ++i) {
        int row_base = wave * 8 + i * 32; // 8 rows = 1024 B per inst
        dma16(wk + row_base * 64 + lane * 8, &w_s[0][row_base * 64]);
    }

    // ---- stage neighbor indices (coalesced), BN*KK = 3456 ints ----
    for (int i = tid; i < BN * KK; i += 256) {
        int hl = i / KK, kx = i - hl * KK;
        int hg = hbase + hl;
        neigh_s[i] = (hg < HH) ? neigh[(size_t)hg * KK + kx] : -1;
    }

    f32x4 acc[8][2];
    #pragma unroll
    for (int mt = 0; mt < 8; ++mt)
        #pragma unroll
        for (int nt = 0; nt < 2; ++nt)
            acc[mt][nt] = (f32x4){0.f, 0.f, 0.f, 0.f};

    __syncthreads();   // neigh_s ready; drains DMA k=0 too

    // ---- B-fragment loader: 4 x 16B direct gathers into VGPRs ----
    int4 cur[2][2], nxt[2][2];
    const int pc_b = (quad * 8);              // element offset of quad's chunk within column
    auto loadB = [&](int kk, int4 (&frag)[2][2]) {
        #pragma unroll
        for (int nt = 0; nt < 2; ++nt) {
            int n = wave * 32 + nt * 16 + col;
            int idx = neigh_s[n * KK + kk];
            if (idx >= 0) {
                const unsigned short* base = xt + (size_t)idx * 64 + pc_b;
                frag[0][nt] = *(const int4*)(base);
                frag[1][nt] = *(const int4*)(base + 32);
            } else {
                frag[0][nt] = make_int4(0, 0, 0, 0);
                frag[1][nt] = make_int4(0, 0, 0, 0);
            }
        }
    };

    loadB(0, cur);

    int p = 0;
    #pragma unroll 1
    for (int k = 0; k < KK; ++k) {
        if (k + 1 < KK) {
            // async W DMA for k+1 into other buffer
            const unsigned short* src = wk + (size_t)(k + 1) * (C_OUT * C_IN);
            #pragma unroll
            for (int i = 0; i < 4; ++i) {
                int row_base = wave * 8 + i * 32;
                dma16(src + row_base * 64 + lane * 8, &w_s[p ^ 1][row_base * 64]);
            }
            loadB(k + 1, nxt);   // latency hidden under MFMA phase below
        }

        // MFMA phase on w_s[p] + cur
        #pragma unroll
        for (int ch = 0; ch < 2; ++ch) {
            const int pc = (ch * 4 + quad) ^ (col & 7);   // physical chunk (XOR swizzle)
            #pragma unroll
            for (int mt = 0; mt < 8; ++mt) {
                s8v a = *(const s8v*)&w_s[p][(mt * 16 + col) * 64 + pc * 8];
                #pragma unroll
                for (int nt = 0; nt < 2; ++nt) {
                    s8v b = __builtin_bit_cast(s8v, cur[ch][nt]);
                    acc[mt][nt] = __builtin_amdgcn_mfma_f32_16x16x32_bf16(a, b, acc[mt][nt], 0, 0, 0);
                }
            }
        }

        __syncthreads();   // drains DMA (k+1) + orders buffer swap across waves
        #pragma unroll
        for (int ch = 0; ch < 2; ++ch)
            #pragma unroll
            for (int nt = 0; nt < 2; ++nt)
                cur[ch][nt] = nxt[ch][nt];
        p ^= 1;
    }

    // ---- epilogue: D row = quad*4+r (o), col = lane&15 (h); relu + fp32 store ----
    #pragma unroll
    for (int mt = 0; mt < 8; ++mt) {
        #pragma unroll
        for (int nt = 0; nt < 2; ++nt) {
            int hg = hbase + wave * 32 + nt * 16 + col;
            if (hg < HH) {
                #pragma unroll
                for (int r = 0; r < 4; ++r) {
                    int o = mt * 16 + quad * 4 + r;
                    float v = acc[mt][nt][r];
                    out[(size_t)o * HH + hg] = v > 0.f ? v : 0.f;
                }
            }
        }
    }
}

extern "C" void kernel_launch(void* const* d_in, const int* in_sizes, int n_in,
                              void* d_out, int out_size, void* d_ws, size_t ws_size,
                              hipStream_t stream) {
    const float* data_in = (const float*)d_in[0];
    const int*   neigh   = (const int*)d_in[1];
    const float* weight  = (const float*)d_in[2];
    float* out = (float*)d_out;

    unsigned short* xt = (unsigned short*)d_ws;            // H*64 bf16 = 12.8 MB
    unsigned short* wk = xt + (size_t)HH * 64;             // 27*128*64 bf16 = 442 KB

    prep_kernel<<<TB + WB, 256, 0, stream>>>(data_in, weight, xt, wk);
    conv_main<<<NBLK, 256, 0, stream>>>(xt, wk, neigh, out);
}